// Round 3
// baseline (218.806 us; speedup 1.0000x reference)
//
#include <hip/hip_runtime.h>
#include <math.h>

typedef __attribute__((ext_vector_type(8))) short short8;
typedef __attribute__((ext_vector_type(4))) float floatx4;

__device__ __forceinline__ float bf2f(unsigned short u) {
    union { unsigned int u; float f; } v;
    v.u = ((unsigned int)u) << 16;
    return v.f;
}

__device__ __forceinline__ unsigned short f2bf(float f) {
    union { float f; unsigned int u; } v;
    v.f = f;
    unsigned int r = v.u + 0x7fffu + ((v.u >> 16) & 1u);  // RNE
    return (unsigned short)(r >> 16);
}

__device__ __forceinline__ void gload16_lds(const void* g, void* l) {
    __builtin_amdgcn_global_load_lds(
        (const __attribute__((address_space(1))) unsigned int*)g,
        (__attribute__((address_space(3))) unsigned int*)l, 16, 0, 0);
}

__device__ __forceinline__ ushort4 cvt4(float4 v, float fa) {
    ushort4 o;
    o.x = f2bf(v.x * fa); o.y = f2bf(v.y * fa);
    o.z = f2bf(v.z * fa); o.w = f2bf(v.w * fa);
    return o;
}

// ---------------- fused prep: rows (wave-per-row) | transpose(value) ----------
__global__ __launch_bounds__(256) void prep_kernel(
    const float* __restrict__ x, const float* __restrict__ key,
    const float* __restrict__ temp, const float* __restrict__ val,
    unsigned short* __restrict__ xb, unsigned short* __restrict__ kf,
    unsigned short* __restrict__ VT, float* __restrict__ rowsq,
    int M, int T, int D, int Dout, int nRowBlocks) {
    const int bid = blockIdx.x;
    if (bid < nRowBlocks) {
        const int lane = threadIdx.x & 63;
        const int nWaves = nRowBlocks << 2;  // 4 waves per block
        const int totRows = M + T;
        for (int row = (bid << 2) | (int)(threadIdx.x >> 6); row < totRows;
             row += nWaves) {
            const bool isx = row < M;
            const int r = isx ? row : row - M;
            const float4* s4 =
                (const float4*)(isx ? (x + (size_t)r * D) : (key + (size_t)r * D));
            float4 v0 = s4[lane];
            float4 v1 = s4[lane + 64];
            float4 v2 = s4[lane + 128];
            float4 v3 = s4[lane + 192];
            float s = v0.x * v0.x + v0.y * v0.y + v0.z * v0.z + v0.w * v0.w;
            s += v1.x * v1.x + v1.y * v1.y + v1.z * v1.z + v1.w * v1.w;
            s += v2.x * v2.x + v2.y * v2.y + v2.z * v2.z + v2.w * v2.w;
            s += v3.x * v3.x + v3.y * v3.y + v3.z * v3.z + v3.w * v3.w;
#pragma unroll
            for (int o = 32; o > 0; o >>= 1) s += __shfl_xor(s, o, 64);
            float fa = 1.0f / fmaxf(sqrtf(s), 1e-12f);
            if (isx) {
                if (lane == 0) rowsq[r] = 0.0f;
            } else {
                fa = fa / (1.0f + expf(-temp[r]));
            }
            ushort4* dst =
                (ushort4*)(isx ? (xb + (size_t)r * D) : (kf + (size_t)r * D));
            dst[lane] = cvt4(v0, fa);
            dst[lane + 64] = cvt4(v1, fa);
            dst[lane + 128] = cvt4(v2, fa);
            dst[lane + 192] = cvt4(v3, fa);
        }
    } else {
        __shared__ unsigned short tile[64][65];
        const int idx = bid - nRowBlocks;
        const int nCt = Dout >> 6;
        const int c0 = (idx % nCt) * 64;
        const int r0 = (idx / nCt) * 64;
        const int t = threadIdx.x;
        for (int i = t; i < 4096; i += 256) {
            int rr = i >> 6, cc = i & 63;
            tile[rr][cc] = f2bf(val[(size_t)(r0 + rr) * Dout + c0 + cc]);
        }
        __syncthreads();
        for (int i = t; i < 4096; i += 256) {
            int rr = i >> 6, cc = i & 63;
            VT[(size_t)(c0 + rr) * T + r0 + cc] = tile[cc][rr];
        }
    }
}

// ===== 256x128 bf16 MFMA GEMM, counted-vmcnt pipeline, 2 blocks/CU ===========
// C[M,N] = A[M,K] * B[N,K]^T.  4 waves (2M x 2N), per-wave 128x64 output
// (same per-wave shape & read/MFMA ratio as the 256^2 version: 12 ds_read_b128
// per 32 MFMA). 3-slot LDS ring: slot = A 16KB (16 subtiles [16][32] bf16) |
// B 8KB (8 subtiles), st_16x32 swizzle (byte5 ^= row-bit3) on BOTH staging
// source lanes and ds_read (rule #21). 72KB/block -> 2 blocks/CU: the two
// resident blocks' barrier rendezvous are independent, so one block's MFMA
// covers the other's lgkm/vmcnt stalls (the R2 1-block lockstep gap).
// Staging: 6 gloads/thread/tile (3 per phase), depth-2 prefetch, vmcnt(6)
// steady-state (never 0 in loop). Liveness: stage of tile t+2 writes slot
// (t+2)%3 == (t-1)%3, which every wave finished reading (lgkm-waited) before
// the last barrier of tile t-1; the gloads are issued after that barrier.
// MODE 0: C(bf16) = acc; rowsq[m] += sum(acc^2)   (GEMM1: sim)
// MODE 1: C(fp32) = acc                           (GEMM2: out)
template <int MODE>
__global__ __launch_bounds__(256, 2) void gemm_pipe(
    const unsigned short* __restrict__ A, const unsigned short* __restrict__ B,
    void* __restrict__ Cv, float* __restrict__ rowsq, int M, int N, int K) {
    __shared__ __align__(16) char smem[73728];  // 3 slots x (A 16KB | B 8KB)
    const int tid = threadIdx.x;
    const int lane = tid & 63;
    const int w = tid >> 6;       // wave 0..3
    const int wr = w >> 1;        // 0..1  (M)
    const int wc = w & 1;         // 0..1  (N)
    const int m0 = blockIdx.x * 256;
    const int n0 = blockIdx.y * 128;
    const int q = lane >> 4;
    const int cl = lane & 15;

    // staging addressing (pre-swizzled global source, rule #21):
    // lane -> subtile row (lane>>2), 16B chunk (lane&3) ^ (row-bit3 = lane&32)
    const int srow = lane >> 2;
    const int sch = (lane & 3) ^ ((lane & 32) >> 4);
    const unsigned short* gA = A + (size_t)(m0 + w * 16 + srow) * K + sch * 8;
    const unsigned short* gB = B + (size_t)(n0 + w * 16 + srow) * K + sch * 8;

    // ds_read per-lane base within a 1KB subtile: (row=cl)*64B + q*16B, swz
    const int LB = ((cl * 64 + q * 16) ^ ((lane & 8) << 2));

    floatx4 acc[8][4];
#pragma unroll
    for (int i = 0; i < 8; i++)
#pragma unroll
        for (int j = 0; j < 4; j++) acc[i][j] = (floatx4){0.f, 0.f, 0.f, 0.f};

    const int NT = K >> 5;  // BK=32 tiles

    // wave w stages A subtiles {w, w+4, w+8, w+12}, B subtiles {w, w+4}
    auto stageA = [&](int t, int j) {
        char* base = smem + (size_t)(t % 3) * 24576 + (w + 4 * j) * 1024;
        gload16_lds(gA + (size_t)j * 64 * K + t * 32, base);
    };
    auto stageB = [&](int t, int j) {
        char* base = smem + (size_t)(t % 3) * 24576 + 16384 + (w + 4 * j) * 1024;
        gload16_lds(gB + (size_t)j * 64 * K + t * 32, base);
    };

    // prologue: stage tiles 0,1 (12 gloads/thread) -> wait tile 0 (6 may fly)
    stageA(0, 0); stageA(0, 1); stageB(0, 0);
    stageA(0, 2); stageA(0, 3); stageB(0, 1);
    stageA(1, 0); stageA(1, 1); stageB(1, 0);
    stageA(1, 2); stageA(1, 3); stageB(1, 1);
    asm volatile("s_waitcnt vmcnt(6)" ::: "memory");
    __builtin_amdgcn_s_barrier();

    for (int tt = 0; tt < NT; ++tt) {
        const char* sA = smem + (size_t)(tt % 3) * 24576;
        const char* sB = sA + 16384;
        const bool st = (tt + 2) < NT;
        short8 bf[4], af[4];
        // ---------------- phase 0: B(all nt) + A(mt 0..3) ----------------
#pragma unroll
        for (int nt = 0; nt < 4; ++nt)
            bf[nt] = *(const short8*)(sB + (wc * 4 + nt) * 1024 + LB);
#pragma unroll
        for (int mt = 0; mt < 4; ++mt)
            af[mt] = *(const short8*)(sA + (wr * 8 + mt) * 1024 + LB);
        if (st) { stageA(tt + 2, 0); stageA(tt + 2, 1); stageB(tt + 2, 0); }
        __builtin_amdgcn_s_barrier();
        asm volatile("s_waitcnt lgkmcnt(0)" ::: "memory");
        __builtin_amdgcn_s_setprio(1);
#pragma unroll
        for (int mt = 0; mt < 4; ++mt)
#pragma unroll
            for (int nt = 0; nt < 4; ++nt)
                acc[mt][nt] = __builtin_amdgcn_mfma_f32_16x16x32_bf16(
                    af[mt], bf[nt], acc[mt][nt], 0, 0, 0);
        __builtin_amdgcn_s_setprio(0);
        __builtin_amdgcn_s_barrier();
        // ---------------- phase 1: A(mt 4..7) ----------------------------
#pragma unroll
        for (int mt = 0; mt < 4; ++mt)
            af[mt] = *(const short8*)(sA + (wr * 8 + 4 + mt) * 1024 + LB);
        if (st) { stageA(tt + 2, 2); stageA(tt + 2, 3); stageB(tt + 2, 1); }
        if (st) {
            asm volatile("s_waitcnt vmcnt(6)" ::: "memory");
        } else if (tt == NT - 2) {
            asm volatile("s_waitcnt vmcnt(0)" ::: "memory");
        }
        __builtin_amdgcn_s_barrier();
        asm volatile("s_waitcnt lgkmcnt(0)" ::: "memory");
        __builtin_amdgcn_s_setprio(1);
#pragma unroll
        for (int mt = 0; mt < 4; ++mt)
#pragma unroll
            for (int nt = 0; nt < 4; ++nt)
                acc[4 + mt][nt] = __builtin_amdgcn_mfma_f32_16x16x32_bf16(
                    af[mt], bf[nt], acc[4 + mt][nt], 0, 0, 0);
        __builtin_amdgcn_s_setprio(0);
        __builtin_amdgcn_s_barrier();
    }

    // epilogue — C/D layout: col = lane&15, row = q*4 + reg
#pragma unroll
    for (int mt = 0; mt < 8; ++mt) {
#pragma unroll
        for (int r = 0; r < 4; ++r) {
            const int m = m0 + wr * 128 + mt * 16 + q * 4 + r;
            if (MODE == 0) {
                unsigned short* C = (unsigned short*)Cv;
                float ssq = 0.f;
#pragma unroll
                for (int nt = 0; nt < 4; ++nt) {
                    float v = acc[mt][nt][r];
                    ssq += v * v;
                    C[(size_t)m * N + n0 + wc * 64 + nt * 16 + cl] = f2bf(v);
                }
#pragma unroll
                for (int o = 1; o < 16; o <<= 1) ssq += __shfl_xor(ssq, o, 64);
                if (cl == 0) atomicAdd(&rowsq[m], ssq);
            } else {
                float* C = (float*)Cv;
#pragma unroll
                for (int nt = 0; nt < 4; ++nt)
                    C[(size_t)m * N + n0 + wc * 64 + nt * 16 + cl] =
                        acc[mt][nt][r];
            }
        }
    }
}

// ---------- in-place: sim = bf16(gelu_exact(sim * sqrt(T)/sqrt(rowsq[row]))) ---
__global__ __launch_bounds__(256) void gelu_kernel(unsigned short* __restrict__ sim,
                                                   const float* __restrict__ rowsq,
                                                   int nVec, int t8shift,
                                                   float sqrtT) {
    const int stride = gridDim.x * blockDim.x;
    const float kk = 0.70710678118654752f;
    for (int i = blockIdx.x * blockDim.x + threadIdx.x; i < nVec; i += stride) {
        short8 v = *(const short8*)(sim + (size_t)i * 8);
        const int row = i >> t8shift;
        const float scale = sqrtT / fmaxf(sqrtf(rowsq[row]), 1e-30f);
        short8 o;
#pragma unroll
        for (int j = 0; j < 8; j++) {
            float z = bf2f((unsigned short)v[j]) * scale;
            o[j] = (short)f2bf(0.5f * z * (1.0f + erff(z * kk)));
        }
        *(short8*)(sim + (size_t)i * 8) = o;
    }
}

extern "C" void kernel_launch(void* const* d_in, const int* in_sizes, int n_in,
                              void* d_out, int out_size, void* d_ws, size_t ws_size,
                              hipStream_t stream) {
    const float* x    = (const float*)d_in[0];  // [M, D] fp32
    const float* key  = (const float*)d_in[1];  // [T, D] fp32
    const float* val  = (const float*)d_in[2];  // [T, Dout] fp32
    const float* temp = (const float*)d_in[3];  // [T] fp32
    float* out = (float*)d_out;                 // [M, Dout] fp32

    const int T = in_sizes[3];              // 1024
    const int D = in_sizes[1] / T;          // 1024
    const int Dout = in_sizes[2] / T;       // 1024
    const int M = in_sizes[0] / D;          // 16384

    char* ws = (char*)d_ws;
    size_t off = 0;
    unsigned short* xb  = (unsigned short*)(ws + off); off += (size_t)M * D * 2;
    unsigned short* sim = (unsigned short*)(ws + off); off += (size_t)M * T * 2;
    unsigned short* kf  = (unsigned short*)(ws + off); off += (size_t)T * D * 2;
    unsigned short* VT  = (unsigned short*)(ws + off); off += (size_t)Dout * T * 2;
    float* rowsq = (float*)(ws + off); off += (size_t)M * 4;
    (void)ws_size; (void)n_in; (void)out_size;

    const int nTrTiles = (T >> 6) * (Dout >> 6);
    const int nRowBlocks = 1024;  // 4096 waves grid-striding M+T rows
    prep_kernel<<<nRowBlocks + nTrTiles, 256, 0, stream>>>(
        x, key, temp, val, xb, kf, VT, rowsq, M, T, D, Dout, nRowBlocks);
    gemm_pipe<0><<<dim3(M / 256, T / 128), 256, 0, stream>>>(xb, kf, sim, rowsq,
                                                             M, T, D);
    int t8shift = 0;
    {
        int t8 = T >> 3;
        while ((1 << t8shift) < t8) t8shift++;
    }
    gelu_kernel<<<2048, 256, 0, stream>>>(sim, rowsq, M * (T >> 3), t8shift,
                                          sqrtf((float)T));
    gemm_pipe<1><<<dim3(M / 256, Dout / 128), 256, 0, stream>>>(sim, VT, out,
                                                                nullptr, M, Dout, T);
}

// Round 5
// 218.306 us; speedup vs baseline: 1.0023x; 1.0023x over previous
//
#include <hip/hip_runtime.h>
#include <math.h>

typedef __attribute__((ext_vector_type(8))) short short8;
typedef __attribute__((ext_vector_type(4))) float floatx4;

__device__ __forceinline__ float bf2f(unsigned short u) {
    union { unsigned int u; float f; } v;
    v.u = ((unsigned int)u) << 16;
    return v.f;
}

__device__ __forceinline__ unsigned short f2bf(float f) {
    union { float f; unsigned int u; } v;
    v.f = f;
    unsigned int r = v.u + 0x7fffu + ((v.u >> 16) & 1u);  // RNE
    return (unsigned short)(r >> 16);
}

__device__ __forceinline__ void gload16_lds(const void* g, void* l) {
    __builtin_amdgcn_global_load_lds(
        (const __attribute__((address_space(1))) unsigned int*)g,
        (__attribute__((address_space(3))) unsigned int*)l, 16, 0, 0);
}

__device__ __forceinline__ ushort4 cvt4(float4 v, float fa) {
    ushort4 o;
    o.x = f2bf(v.x * fa); o.y = f2bf(v.y * fa);
    o.z = f2bf(v.z * fa); o.w = f2bf(v.w * fa);
    return o;
}

// ---------------- fused prep: rows (wave-per-row) | transpose(value) ----------
__global__ __launch_bounds__(256) void prep_kernel(
    const float* __restrict__ x, const float* __restrict__ key,
    const float* __restrict__ temp, const float* __restrict__ val,
    unsigned short* __restrict__ xb, unsigned short* __restrict__ kf,
    unsigned short* __restrict__ VT, float* __restrict__ rowsq,
    int M, int T, int D, int Dout, int nRowBlocks) {
    const int bid = blockIdx.x;
    if (bid < nRowBlocks) {
        const int lane = threadIdx.x & 63;
        const int nWaves = nRowBlocks << 2;  // 4 waves per block
        const int totRows = M + T;
        for (int row = (bid << 2) | (int)(threadIdx.x >> 6); row < totRows;
             row += nWaves) {
            const bool isx = row < M;
            const int r = isx ? row : row - M;
            const float4* s4 =
                (const float4*)(isx ? (x + (size_t)r * D) : (key + (size_t)r * D));
            float4 v0 = s4[lane];
            float4 v1 = s4[lane + 64];
            float4 v2 = s4[lane + 128];
            float4 v3 = s4[lane + 192];
            float s = v0.x * v0.x + v0.y * v0.y + v0.z * v0.z + v0.w * v0.w;
            s += v1.x * v1.x + v1.y * v1.y + v1.z * v1.z + v1.w * v1.w;
            s += v2.x * v2.x + v2.y * v2.y + v2.z * v2.z + v2.w * v2.w;
            s += v3.x * v3.x + v3.y * v3.y + v3.z * v3.z + v3.w * v3.w;
#pragma unroll
            for (int o = 32; o > 0; o >>= 1) s += __shfl_xor(s, o, 64);
            float fa = 1.0f / fmaxf(sqrtf(s), 1e-12f);
            if (isx) {
                if (lane == 0) rowsq[r] = 0.0f;
            } else {
                fa = fa / (1.0f + expf(-temp[r]));
            }
            ushort4* dst =
                (ushort4*)(isx ? (xb + (size_t)r * D) : (kf + (size_t)r * D));
            dst[lane] = cvt4(v0, fa);
            dst[lane + 64] = cvt4(v1, fa);
            dst[lane + 128] = cvt4(v2, fa);
            dst[lane + 192] = cvt4(v3, fa);
        }
    } else {
        __shared__ unsigned short tile[64][65];
        const int idx = bid - nRowBlocks;
        const int nCt = Dout >> 6;
        const int c0 = (idx % nCt) * 64;
        const int r0 = (idx / nCt) * 64;
        const int t = threadIdx.x;
        for (int i = t; i < 4096; i += 256) {
            int rr = i >> 6, cc = i & 63;
            tile[rr][cc] = f2bf(val[(size_t)(r0 + rr) * Dout + c0 + cc]);
        }
        __syncthreads();
        for (int i = t; i < 4096; i += 256) {
            int rr = i >> 6, cc = i & 63;
            VT[(size_t)(c0 + rr) * T + r0 + cc] = tile[cc][rr];
        }
    }
}

// ===== 256x128 bf16 MFMA GEMM, counted-vmcnt pipeline, 2 blocks/CU ===========
// Same geometry/schedule as R3 (4 waves 2Mx2N, per-wave 128x64, 3-slot LDS
// ring 72KB, st_16x32 swizzle both-sides, vmcnt(6) steady, 2 barriers/phase).
// Changes vs R3 (WAR de-serialization + const addressing):
//  * K-loop unrolled x6: slot (t%3) and tile parity (t%2) are compile-time,
//    so every ds_read/gload LDS address is base + immediate (no ring VALU).
//  * Fragment buffers rotated: af0 (phase0), af1 (phase1), bf0/bf1 by tile
//    parity. Every ds_read writes VGPRs whose last in-flight MFMA reader is
//    >=2 phases old -> no WAR scoreboard stall against the MFMA pipe, so
//    phase p+1's LDS reads overlap phase p's MFMA drain.
//  * Rule #18: sched_barrier(0) after every inline-asm lgkmcnt(0) so hipcc
//    cannot hoist register-only MFMAs above the wait.
// K=1024 -> NT=32 tiles: 5 groups of 6 (tiles 0..29) + explicit tail 30,31.
template <int MODE>
__global__ __launch_bounds__(256, 2) void gemm_pipe(
    const unsigned short* __restrict__ A, const unsigned short* __restrict__ B,
    void* __restrict__ Cv, float* __restrict__ rowsq, int M, int N, int K) {
    __shared__ __align__(16) char smem[73728];  // 3 slots x (A 16KB | B 8KB)
    const int tid = threadIdx.x;
    const int lane = tid & 63;
    const int w = tid >> 6;       // wave 0..3
    const int wr = w >> 1;        // 0..1  (M)
    const int wc = w & 1;         // 0..1  (N)
    const int m0 = blockIdx.x * 256;
    const int n0 = blockIdx.y * 128;
    const int q = lane >> 4;
    const int cl = lane & 15;

    // staging addressing (pre-swizzled global source, rule #21)
    const int srow = lane >> 2;
    const int sch = (lane & 3) ^ ((lane & 32) >> 4);
    const unsigned short* gA = A + (size_t)(m0 + w * 16 + srow) * K + sch * 8;
    const unsigned short* gB = B + (size_t)(n0 + w * 16 + srow) * K + sch * 8;
    // row-group base pointers (advance by 192 elems per 6-tile group)
    const unsigned short* rA0 = gA;
    const unsigned short* rA1 = gA + (size_t)64 * K;
    const unsigned short* rA2 = gA + (size_t)128 * K;
    const unsigned short* rA3 = gA + (size_t)192 * K;
    const unsigned short* rB0 = gB;
    const unsigned short* rB1 = gB + (size_t)64 * K;

    // LDS staging dest bases (wave-uniform; HW appends lane*16)
    char* stA = smem + w * 1024;
    char* stB = stA + 16384;

    // ds_read per-lane bases (swizzled), byte offsets into smem
    const int LB = ((cl * 64 + q * 16) ^ ((lane & 8) << 2));
    const char* rdA = (const char*)smem + LB + wr * 8192;
    const char* rdB = (const char*)smem + LB + 16384 + wc * 4096;

    floatx4 acc[8][4];
#pragma unroll
    for (int i = 0; i < 8; i++)
#pragma unroll
        for (int j = 0; j < 4; j++) acc[i][j] = (floatx4){0.f, 0.f, 0.f, 0.f};

    short8 af0[4], af1[4], bf0[4], bf1[4];

    // prologue: stage tiles 0 (slot 0) and 1 (slot 1); wait tile 0 (6 fly)
    gload16_lds(rA0, stA);
    gload16_lds(rA1, stA + 4096);
    gload16_lds(rB0, stB);
    gload16_lds(rA2, stA + 8192);
    gload16_lds(rA3, stA + 12288);
    gload16_lds(rB1, stB + 4096);
    gload16_lds(rA0 + 32, stA + 24576);
    gload16_lds(rA1 + 32, stA + 24576 + 4096);
    gload16_lds(rB0 + 32, stB + 24576);
    gload16_lds(rA2 + 32, stA + 24576 + 8192);
    gload16_lds(rA3 + 32, stA + 24576 + 12288);
    gload16_lds(rB1 + 32, stB + 24576 + 4096);
    asm volatile("s_waitcnt vmcnt(6)" ::: "memory");
    __builtin_amdgcn_s_barrier();
    // group pointers pre-offset to tile 2 (staged during tile 0)
    rA0 += 64; rA1 += 64; rA2 += 64; rA3 += 64; rB0 += 64; rB1 += 64;

#define MFMA16(AF, BF, RO)                                                   \
    _Pragma("unroll") for (int mt = 0; mt < 4; ++mt)                         \
        _Pragma("unroll") for (int nt = 0; nt < 4; ++nt)                     \
            acc[RO + mt][nt] = __builtin_amdgcn_mfma_f32_16x16x32_bf16(      \
                AF[mt], BF[nt], acc[RO + mt][nt], 0, 0, 0);

// one BK=32 tile, steady state: read slot SLOT, stage (tile+2) into SSLOT at
// k-elem-offset KOFF (immediate), bf buffer BF (tile parity)
#define TILE(SLOT, SSLOT, BF, KOFF)                                          \
    {                                                                        \
        BF[0] = *(const short8*)(rdB + SLOT * 24576);                        \
        BF[1] = *(const short8*)(rdB + SLOT * 24576 + 1024);                 \
        BF[2] = *(const short8*)(rdB + SLOT * 24576 + 2048);                 \
        BF[3] = *(const short8*)(rdB + SLOT * 24576 + 3072);                 \
        af0[0] = *(const short8*)(rdA + SLOT * 24576);                       \
        af0[1] = *(const short8*)(rdA + SLOT * 24576 + 1024);                \
        af0[2] = *(const short8*)(rdA + SLOT * 24576 + 2048);                \
        af0[3] = *(const short8*)(rdA + SLOT * 24576 + 3072);                \
        gload16_lds(rA0 + KOFF, stA + SSLOT * 24576);                        \
        gload16_lds(rA1 + KOFF, stA + SSLOT * 24576 + 4096);                 \
        gload16_lds(rB0 + KOFF, stB + SSLOT * 24576);                        \
        __builtin_amdgcn_s_barrier();                                        \
        asm volatile("s_waitcnt lgkmcnt(0)" ::: "memory");                   \
        __builtin_amdgcn_sched_barrier(0);                                   \
        __builtin_amdgcn_s_setprio(1);                                       \
        MFMA16(af0, BF, 0)                                                   \
        __builtin_amdgcn_s_setprio(0);                                       \
        __builtin_amdgcn_s_barrier();                                        \
        af1[0] = *(const short8*)(rdA + SLOT * 24576 + 4096);                \
        af1[1] = *(const short8*)(rdA + SLOT * 24576 + 5120);                \
        af1[2] = *(const short8*)(rdA + SLOT * 24576 + 6144);                \
        af1[3] = *(const short8*)(rdA + SLOT * 24576 + 7168);                \
        gload16_lds(rA2 + KOFF, stA + SSLOT * 24576 + 8192);                 \
        gload16_lds(rA3 + KOFF, stA + SSLOT * 24576 + 12288);                \
        gload16_lds(rB1 + KOFF, stB + SSLOT * 24576 + 4096);                 \
        asm volatile("s_waitcnt vmcnt(6)" ::: "memory");                     \
        __builtin_amdgcn_s_barrier();                                        \
        asm volatile("s_waitcnt lgkmcnt(0)" ::: "memory");                   \
        __builtin_amdgcn_sched_barrier(0);                                   \
        __builtin_amdgcn_s_setprio(1);                                       \
        MFMA16(af1, BF, 4)                                                   \
        __builtin_amdgcn_s_setprio(0);                                       \
        __builtin_amdgcn_s_barrier();                                        \
    }

// tail tile: no staging; DRAIN=1 -> vmcnt(0) at the steady vmcnt slot
#define TILE_TAIL(SLOT, BF, DRAIN)                                           \
    {                                                                        \
        BF[0] = *(const short8*)(rdB + SLOT * 24576);                        \
        BF[1] = *(const short8*)(rdB + SLOT * 24576 + 1024);                 \
        BF[2] = *(const short8*)(rdB + SLOT * 24576 + 2048);                 \
        BF[3] = *(const short8*)(rdB + SLOT * 24576 + 3072);                 \
        af0[0] = *(const short8*)(rdA + SLOT * 24576);                       \
        af0[1] = *(const short8*)(rdA + SLOT * 24576 + 1024);                \
        af0[2] = *(const short8*)(rdA + SLOT * 24576 + 2048);                \
        af0[3] = *(const short8*)(rdA + SLOT * 24576 + 3072);                \
        __builtin_amdgcn_s_barrier();                                        \
        asm volatile("s_waitcnt lgkmcnt(0)" ::: "memory");                   \
        __builtin_amdgcn_sched_barrier(0);                                   \
        __builtin_amdgcn_s_setprio(1);                                       \
        MFMA16(af0, BF, 0)                                                   \
        __builtin_amdgcn_s_setprio(0);                                       \
        __builtin_amdgcn_s_barrier();                                        \
        af1[0] = *(const short8*)(rdA + SLOT * 24576 + 4096);                \
        af1[1] = *(const short8*)(rdA + SLOT * 24576 + 5120);                \
        af1[2] = *(const short8*)(rdA + SLOT * 24576 + 6144);                \
        af1[3] = *(const short8*)(rdA + SLOT * 24576 + 7168);                \
        if (DRAIN) asm volatile("s_waitcnt vmcnt(0)" ::: "memory");          \
        __builtin_amdgcn_s_barrier();                                        \
        asm volatile("s_waitcnt lgkmcnt(0)" ::: "memory");                   \
        __builtin_amdgcn_sched_barrier(0);                                   \
        __builtin_amdgcn_s_setprio(1);                                       \
        MFMA16(af1, BF, 4)                                                   \
        __builtin_amdgcn_s_setprio(0);                                       \
        __builtin_amdgcn_s_barrier();                                        \
    }

    // main: 5 groups x 6 tiles (0..29); slot=t%3, stage slot=(t+2)%3,
    // bf parity=t%2, staged k-offset immediate = (t%6)*32 elems
    for (int g = 0; g < 5; ++g) {
        TILE(0, 2, bf0, 0)
        TILE(1, 0, bf1, 32)
        TILE(2, 1, bf0, 64)
        TILE(0, 2, bf1, 96)
        TILE(1, 0, bf0, 128)
        TILE(2, 1, bf1, 160)
        rA0 += 192; rA1 += 192; rA2 += 192; rA3 += 192;
        rB0 += 192; rB1 += 192;
    }
    // tail: tiles 30 (slot 0, drain) and 31 (slot 1)
    TILE_TAIL(0, bf0, 1)
    TILE_TAIL(1, bf1, 0)

#undef TILE
#undef TILE_TAIL
#undef MFMA16

    // epilogue — C/D layout: col = lane&15, row = q*4 + reg
#pragma unroll
    for (int mt = 0; mt < 8; ++mt) {
#pragma unroll
        for (int r = 0; r < 4; ++r) {
            const int m = m0 + wr * 128 + mt * 16 + q * 4 + r;
            if (MODE == 0) {
                unsigned short* C = (unsigned short*)Cv;
                float ssq = 0.f;
#pragma unroll
                for (int nt = 0; nt < 4; ++nt) {
                    float v = acc[mt][nt][r];
                    ssq += v * v;
                    C[(size_t)m * N + n0 + wc * 64 + nt * 16 + cl] = f2bf(v);
                }
#pragma unroll
                for (int o = 1; o < 16; o <<= 1) ssq += __shfl_xor(ssq, o, 64);
                if (cl == 0) atomicAdd(&rowsq[m], ssq);
            } else {
                float* C = (float*)Cv;
#pragma unroll
                for (int nt = 0; nt < 4; ++nt)
                    C[(size_t)m * N + n0 + wc * 64 + nt * 16 + cl] =
                        acc[mt][nt][r];
            }
        }
    }
}

// ---------- in-place: sim = bf16(gelu_exact(sim * sqrt(T)/sqrt(rowsq[row]))) ---
__global__ __launch_bounds__(256) void gelu_kernel(unsigned short* __restrict__ sim,
                                                   const float* __restrict__ rowsq,
                                                   int nVec, int t8shift,
                                                   float sqrtT) {
    const int stride = gridDim.x * blockDim.x;
    const float kk = 0.70710678118654752f;
    for (int i = blockIdx.x * blockDim.x + threadIdx.x; i < nVec; i += stride) {
        short8 v = *(const short8*)(sim + (size_t)i * 8);
        const int row = i >> t8shift;
        const float scale = sqrtT / fmaxf(sqrtf(rowsq[row]), 1e-30f);
        short8 o;
#pragma unroll
        for (int j = 0; j < 8; j++) {
            float z = bf2f((unsigned short)v[j]) * scale;
            o[j] = (short)f2bf(0.5f * z * (1.0f + erff(z * kk)));
        }
        *(short8*)(sim + (size_t)i * 8) = o;
    }
}

extern "C" void kernel_launch(void* const* d_in, const int* in_sizes, int n_in,
                              void* d_out, int out_size, void* d_ws, size_t ws_size,
                              hipStream_t stream) {
    const float* x    = (const float*)d_in[0];  // [M, D] fp32
    const float* key  = (const float*)d_in[1];  // [T, D] fp32
    const float* val  = (const float*)d_in[2];  // [T, Dout] fp32
    const float* temp = (const float*)d_in[3];  // [T] fp32
    float* out = (float*)d_out;                 // [M, Dout] fp32

    const int T = in_sizes[3];              // 1024
    const int D = in_sizes[1] / T;          // 1024
    const int Dout = in_sizes[2] / T;       // 1024
    const int M = in_sizes[0] / D;          // 16384

    char* ws = (char*)d_ws;
    size_t off = 0;
    unsigned short* xb  = (unsigned short*)(ws + off); off += (size_t)M * D * 2;
    unsigned short* sim = (unsigned short*)(ws + off); off += (size_t)M * T * 2;
    unsigned short* kf  = (unsigned short*)(ws + off); off += (size_t)T * D * 2;
    unsigned short* VT  = (unsigned short*)(ws + off); off += (size_t)Dout * T * 2;
    float* rowsq = (float*)(ws + off); off += (size_t)M * 4;
    (void)ws_size; (void)n_in; (void)out_size;

    const int nTrTiles = (T >> 6) * (Dout >> 6);
    const int nRowBlocks = 1024;  // 4096 waves grid-striding M+T rows
    prep_kernel<<<nRowBlocks + nTrTiles, 256, 0, stream>>>(
        x, key, temp, val, xb, kf, VT, rowsq, M, T, D, Dout, nRowBlocks);
    gemm_pipe<0><<<dim3(M / 256, T / 128), 256, 0, stream>>>(xb, kf, sim, rowsq,
                                                             M, T, D);
    int t8shift = 0;
    {
        int t8 = T >> 3;
        while ((1 << t8shift) < t8) t8shift++;
    }
    gelu_kernel<<<2048, 256, 0, stream>>>(sim, rowsq, M * (T >> 3), t8shift,
                                          sqrtf((float)T));
    gemm_pipe<1><<<dim3(M / 256, Dout / 128), 256, 0, stream>>>(sim, VT, out,
                                                                nullptr, M, Dout, T);
}